// Round 6
// baseline (2639.926 us; speedup 1.0000x reference)
//
#include <hip/hip_runtime.h>

#define THREADS 256
#define SCAN_ITEMS 8    // 2048 elements per scan block
#define NSB 256         // scatter/histogram blocks
#define BKT_MAX 1600    // >= ceil(N/64)

typedef float f32x4 __attribute__((ext_vector_type(4)));
typedef __bf16 bf16x8 __attribute__((ext_vector_type(8)));

__device__ inline unsigned short f32_to_bf16_rne(float f) {
    unsigned int u = __float_as_uint(f);
    unsigned int r = u + 0x7fffu + ((u >> 16) & 1u);
    return (unsigned short)(r >> 16);
}
__device__ inline float bf16_bits_to_f32(unsigned short h) {
    return __uint_as_float(((unsigned int)h) << 16);
}
__device__ inline uint4 pack8(const unsigned short* s) {
    uint4 u;
    u.x = (unsigned int)s[0] | ((unsigned int)s[1] << 16);
    u.y = (unsigned int)s[2] | ((unsigned int)s[3] << 16);
    u.z = (unsigned int)s[4] | ((unsigned int)s[5] << 16);
    u.w = (unsigned int)s[6] | ((unsigned int)s[7] << 16);
    return u;
}

// ---------------- coarse counting sort (64-node buckets) ----------------
// Pass 1: per-block private LDS histogram -> hist[bucket*NSB + blk]
__global__ __launch_bounds__(256) void hist_kernel(const int* __restrict__ dst,
                                                   int* __restrict__ hist,
                                                   int E, int nbkt, int chunk) {
    __shared__ int lh[BKT_MAX];
    const int tid = threadIdx.x, blk = blockIdx.x;
    for (int i = tid; i < nbkt; i += 256) lh[i] = 0;
    __syncthreads();
    int s = blk * chunk, e = s + chunk; if (e > E) e = E;
    for (int i = s + tid; i < e; i += 256) atomicAdd(&lh[dst[i] >> 6], 1);
    __syncthreads();
    for (int i = tid; i < nbkt; i += 256) hist[i * NSB + blk] = lh[i];
}

__global__ void scan1_kernel(const int* __restrict__ cnt, int* __restrict__ off,
                             int* __restrict__ bsums, int n) {
    __shared__ int sdata[THREADS];
    int base = blockIdx.x * (THREADS * SCAN_ITEMS) + threadIdx.x * SCAN_ITEMS;
    int vals[SCAN_ITEMS];
    int tsum = 0;
#pragma unroll
    for (int k = 0; k < SCAN_ITEMS; k++) {
        int idx = base + k;
        int v = (idx < n) ? cnt[idx] : 0;
        vals[k] = tsum;
        tsum += v;
    }
    sdata[threadIdx.x] = tsum;
    __syncthreads();
    for (int s = 1; s < THREADS; s <<= 1) {
        int y = (threadIdx.x >= (unsigned)s) ? sdata[threadIdx.x - s] : 0;
        __syncthreads();
        sdata[threadIdx.x] += y;
        __syncthreads();
    }
    int texcl = sdata[threadIdx.x] - tsum;
#pragma unroll
    for (int k = 0; k < SCAN_ITEMS; k++) {
        int idx = base + k;
        if (idx < n) off[idx] = texcl + vals[k];
    }
    if (threadIdx.x == THREADS - 1) bsums[blockIdx.x] = sdata[THREADS - 1];
}

__global__ void scan2_kernel(const int* __restrict__ bsums, int* __restrict__ bbase,
                             int nb, int* __restrict__ offN) {
    if (threadIdx.x == 0 && blockIdx.x == 0) {
        int run = 0;
        for (int i = 0; i < nb; i++) { bbase[i] = run; run += bsums[i]; }
        *offN = run;
    }
}

// add scanned block bases in-place
__global__ void scan3b_kernel(int* __restrict__ off, const int* __restrict__ bbase, int n) {
    int i = blockIdx.x * blockDim.x + threadIdx.x;
    if (i < n) off[i] += bbase[i >> 11];
}

// Pass 2: stable scatter into bucket-grouped array. Each (blk,bucket) run is
// written to consecutive addresses; per-XCD dirty window ~1.6 MB < L2; edge
// stream read once -> no dirty-line thrash. Payload: src | dst_local<<17.
__global__ __launch_bounds__(256) void scatter_kernel(const int* __restrict__ src,
                                                      const int* __restrict__ dst,
                                                      const int* __restrict__ hstS,
                                                      int* __restrict__ esrt,
                                                      int E, int nbkt, int chunk) {
    __shared__ int cur[BKT_MAX];
    const int tid = threadIdx.x, blk = blockIdx.x;
    for (int i = tid; i < nbkt; i += 256) cur[i] = hstS[i * NSB + blk];
    __syncthreads();
    int s = blk * chunk, e = s + chunk; if (e > E) e = E;
    for (int i = s + tid; i < e; i += 256) {
        int d = dst[i];
        int b = d >> 6;
        int p = atomicAdd(&cur[b], 1);
        esrt[p] = src[i] | ((d & 63) << 17);
    }
}

// ---------------- precision prep ----------------
__global__ void cvt_bf16_kernel(const float4* __restrict__ x, ushort4* __restrict__ o, int n4) {
    int i = blockIdx.x * blockDim.x + threadIdx.x;
    if (i < n4) {
        float4 v = x[i];
        ushort4 r;
        r.x = f32_to_bf16_rne(v.x);
        r.y = f32_to_bf16_rne(v.y);
        r.z = f32_to_bf16_rne(v.z);
        r.w = f32_to_bf16_rne(v.w);
        o[i] = r;
    }
}

// Swizzled hi/lo bf16 weights. W256[k][n]: k<128 -> Wn, else Wr.
// [t(8)][nt(8)][plane(2)][lane(64)] x 16B; B frag: n = lane&15, k = t*32+(lane>>4)*8+j.
__global__ void swizzle_w_kernel(const float* __restrict__ Wn, const float* __restrict__ Wr,
                                 uint4* __restrict__ out) {
    int id = blockIdx.x * blockDim.x + threadIdx.x;
    if (id >= 4096) return;
    int lane = id & 63;
    int nt = (id >> 6) & 7;
    int t = id >> 9;
    int kbase = t * 32 + (lane >> 4) * 8;
    int col = nt * 16 + (lane & 15);
    unsigned short hi[8], lo[8];
#pragma unroll
    for (int j = 0; j < 8; j++) {
        int k = kbase + j;
        const float* W = (k < 128) ? (Wn + (size_t)k * 128) : (Wr + (size_t)(k - 128) * 128);
        float v = W[col];
        unsigned short h = f32_to_bf16_rne(v);
        hi[j] = h;
        lo[j] = f32_to_bf16_rne(v - bf16_bits_to_f32(h));
    }
    out[(size_t)((t * 8 + nt) * 2 + 0) * 64 + lane] = pack8(hi);
    out[(size_t)((t * 8 + nt) * 2 + 1) * 64 + lane] = pack8(lo);
}

// ---------------- fused aggregation: one block per 64-node bucket ----------------
// LDS fp32 accumulators [64][128] + LDS degree; edges arrive bucket-grouped.
// Per edge: all 64 lanes gather one dword (2 bf16 feats) of row src and
// ds-atomic-add into acc[dst_local]. No exact CSR needed.
__global__ __launch_bounds__(256, 4) void agg_fused(const unsigned short* __restrict__ hb,
                                                    const int* __restrict__ hstS,
                                                    const int* __restrict__ esrt,
                                                    unsigned short* __restrict__ aggb,
                                                    int E, int nbkt, int n) {
    __shared__ float acc[64 * 128];   // 32 KB
    __shared__ int stage[1024];       // 4 KB
    __shared__ int deg[64];
    const int tid = threadIdx.x, lane = tid & 63, w = tid >> 6;
    const int b = blockIdx.x;

    float4* a4 = (float4*)acc;
    for (int i = tid; i < 2048; i += 256) a4[i] = make_float4(0.f, 0.f, 0.f, 0.f);
    if (tid < 64) deg[tid] = 0;
    __syncthreads();

    const int p0 = hstS[b * NSB];
    const int p1 = (b == nbkt - 1) ? E : hstS[(b + 1) * NSB];

    for (int base = p0; base < p1; base += 1024) {
        int m = p1 - base; if (m > 1024) m = 1024;
        for (int i = tid; i < m; i += 256) stage[i] = esrt[base + i];
        __syncthreads();
        for (int q = w * 64; q < m; q += 256) {
            int mm = m - q; if (mm > 64) mm = 64;
            int pk = (lane < mm) ? stage[q + lane] : 0;
            if (lane < mm) atomicAdd(&deg[(pk >> 17) & 63], 1);
            int u = 0;
            for (; u + 16 <= mm; u += 16) {
                unsigned int v[16]; int dl[16];
#pragma unroll
                for (int j = 0; j < 16; j++) {
                    int pkj = __shfl(pk, u + j);
                    int sj = pkj & 0x1FFFF;
                    dl[j] = (pkj >> 17) & 63;
                    v[j] = *(const unsigned int*)(hb + (size_t)sj * 128 + lane * 2);
                }
#pragma unroll
                for (int j = 0; j < 16; j++) {
                    atomicAdd(&acc[dl[j] * 128 + lane * 2],     __uint_as_float(v[j] << 16));
                    atomicAdd(&acc[dl[j] * 128 + lane * 2 + 1], __uint_as_float(v[j] & 0xffff0000u));
                }
            }
            for (; u < mm; u++) {
                int pkj = __shfl(pk, u);
                int sj = pkj & 0x1FFFF;
                int dlj = (pkj >> 17) & 63;
                unsigned int vv = *(const unsigned int*)(hb + (size_t)sj * 128 + lane * 2);
                atomicAdd(&acc[dlj * 128 + lane * 2],     __uint_as_float(vv << 16));
                atomicAdd(&acc[dlj * 128 + lane * 2 + 1], __uint_as_float(vv & 0xffff0000u));
            }
        }
        __syncthreads();
    }

    // writeout: wave w -> 16 nodes; lane covers 32 feats (bf16-packed dwords)
    int node_l = w * 16 + (lane >> 2);
    int gnode = b * 64 + node_l;
    if (gnode < n) {
        int d = deg[node_l];
        float inv = 1.0f / (float)(d > 1 ? d : 1);
        int fb = (lane & 3) * 32;
        unsigned int ow[16];
#pragma unroll
        for (int j = 0; j < 16; j++) {
            float x0 = acc[node_l * 128 + fb + 2 * j] * inv;
            float x1 = acc[node_l * 128 + fb + 2 * j + 1] * inv;
            ow[j] = (unsigned int)f32_to_bf16_rne(x0) | ((unsigned int)f32_to_bf16_rne(x1) << 16);
        }
        uint4* op = (uint4*)((unsigned int*)aggb + (size_t)gnode * 64 + (lane & 3) * 16);
#pragma unroll
        for (int j = 0; j < 4; j++)
            op[j] = make_uint4(ow[4 * j], ow[4 * j + 1], ow[4 * j + 2], ow[4 * j + 3]);
    }
}

// ---------------- fused SAGE update via split-bf16 MFMA ----------------
template <int LAYER, bool FINAL>
__global__ __launch_bounds__(256, 2) void update_mfma(
    const unsigned short* __restrict__ aggb, const void* __restrict__ hsrc,
    const uint4* __restrict__ Wsw, const float* __restrict__ bias,
    unsigned short* __restrict__ hout,
    const float* __restrict__ Wh, const float* __restrict__ bh,
    float* __restrict__ logits, int n) {
    __shared__ uint4 Alds[2048];
    __shared__ uint4 Wlds[2048];
    const int tid = threadIdx.x;
    const int lane = tid & 63;
    const int w = tid >> 6;
    const int i0 = blockIdx.x * 128;

    f32x4 acc[2][8];
#pragma unroll
    for (int mt = 0; mt < 2; mt++)
#pragma unroll
        for (int nt = 0; nt < 8; nt++) acc[mt][nt] = (f32x4)0.f;

    const int r = tid >> 1;
    const int half = tid & 1;
    const int rg = i0 + r;
    const bool inb = rg < n;
    const int mt_s = r >> 4;
    const int lidx = r & 15;

    for (int c = 0; c < 4; c++) {
        const bool haslo = (LAYER == 0 && c >= 2);
        {
            const uint4* srcW = Wsw + (size_t)c * 2048;
#pragma unroll
            for (int g = 0; g < 8; g++) Wlds[g * 256 + tid] = srcW[g * 256 + tid];
        }
        {
            unsigned short hiA[32], loA[32];
            if (LAYER == 0 && c >= 2) {
                const float4* s4 = (const float4*)((const float*)hsrc + (size_t)rg * 128 +
                                                   (c - 2) * 64 + half * 32);
#pragma unroll
                for (int q = 0; q < 8; q++) {
                    float4 f = inb ? s4[q] : make_float4(0.f, 0.f, 0.f, 0.f);
                    float vv[4] = {f.x, f.y, f.z, f.w};
#pragma unroll
                    for (int e = 0; e < 4; e++) {
                        unsigned short h = f32_to_bf16_rne(vv[e]);
                        hiA[q * 4 + e] = h;
                        loA[q * 4 + e] = f32_to_bf16_rne(vv[e] - bf16_bits_to_f32(h));
                    }
                }
            } else {
                const unsigned short* bsrc = (c < 2) ? aggb : (const unsigned short*)hsrc;
                int cc = (c < 2) ? c : c - 2;
                const uint4* s4 = (const uint4*)(bsrc + (size_t)rg * 128 + cc * 64 + half * 32);
#pragma unroll
                for (int q = 0; q < 4; q++) {
                    uint4 u = inb ? s4[q] : make_uint4(0, 0, 0, 0);
                    unsigned int uu[4] = {u.x, u.y, u.z, u.w};
#pragma unroll
                    for (int e = 0; e < 4; e++) {
                        hiA[q * 8 + e * 2 + 0] = (unsigned short)(uu[e] & 0xffffu);
                        hiA[q * 8 + e * 2 + 1] = (unsigned short)(uu[e] >> 16);
                    }
                }
            }
            unsigned int baseHi = ((mt_s * 2 + half) * 2 + 0) * 64;
#pragma unroll
            for (int g2 = 0; g2 < 4; g2++)
                Alds[baseHi + lidx + 16 * g2] = pack8(&hiA[g2 * 8]);
            if (haslo) {
#pragma unroll
                for (int g2 = 0; g2 < 4; g2++)
                    Alds[baseHi + 64 + lidx + 16 * g2] = pack8(&loA[g2 * 8]);
            }
        }
        __syncthreads();
#pragma unroll
        for (int kt = 0; kt < 2; kt++) {
            bf16x8 a0h = *(const bf16x8*)&Alds[(((w * 2 + 0) * 2 + kt) * 2 + 0) * 64 + lane];
            bf16x8 a1h = *(const bf16x8*)&Alds[(((w * 2 + 1) * 2 + kt) * 2 + 0) * 64 + lane];
            bf16x8 a0l, a1l;
            if (haslo) {
                a0l = *(const bf16x8*)&Alds[(((w * 2 + 0) * 2 + kt) * 2 + 1) * 64 + lane];
                a1l = *(const bf16x8*)&Alds[(((w * 2 + 1) * 2 + kt) * 2 + 1) * 64 + lane];
            }
#pragma unroll
            for (int nt = 0; nt < 8; nt++) {
                bf16x8 bhv = *(const bf16x8*)&Wlds[((kt * 8 + nt) * 2 + 0) * 64 + lane];
                bf16x8 blv = *(const bf16x8*)&Wlds[((kt * 8 + nt) * 2 + 1) * 64 + lane];
                acc[0][nt] = __builtin_amdgcn_mfma_f32_16x16x32_bf16(a0h, bhv, acc[0][nt], 0, 0, 0);
                acc[0][nt] = __builtin_amdgcn_mfma_f32_16x16x32_bf16(a0h, blv, acc[0][nt], 0, 0, 0);
                acc[1][nt] = __builtin_amdgcn_mfma_f32_16x16x32_bf16(a1h, bhv, acc[1][nt], 0, 0, 0);
                acc[1][nt] = __builtin_amdgcn_mfma_f32_16x16x32_bf16(a1h, blv, acc[1][nt], 0, 0, 0);
                if (haslo) {
                    acc[0][nt] = __builtin_amdgcn_mfma_f32_16x16x32_bf16(a0l, bhv, acc[0][nt], 0, 0, 0);
                    acc[1][nt] = __builtin_amdgcn_mfma_f32_16x16x32_bf16(a1l, bhv, acc[1][nt], 0, 0, 0);
                }
            }
        }
        __syncthreads();
    }

    const int col = lane & 15;
    const int g4 = lane >> 4;
    float bcol[8];
#pragma unroll
    for (int nt = 0; nt < 8; nt++) bcol[nt] = bias[nt * 16 + col];
    if (!FINAL) {
#pragma unroll
        for (int mt = 0; mt < 2; mt++) {
            int nodeBase = i0 + (w * 2 + mt) * 16 + g4 * 4;
#pragma unroll
            for (int reg = 0; reg < 4; reg++) {
                int node = nodeBase + reg;
                if (node < n) {
#pragma unroll
                    for (int nt = 0; nt < 8; nt++) {
                        float v = acc[mt][nt][reg] + bcol[nt];
                        v = v > 0.f ? v : 0.f;
                        hout[(size_t)node * 128 + nt * 16 + col] = f32_to_bf16_rne(v);
                    }
                }
            }
        }
    } else {
        float whc[8];
#pragma unroll
        for (int nt = 0; nt < 8; nt++) whc[nt] = Wh[nt * 16 + col];
        float bhv = bh[0];
#pragma unroll
        for (int mt = 0; mt < 2; mt++) {
            int nodeBase = i0 + (w * 2 + mt) * 16 + g4 * 4;
#pragma unroll
            for (int reg = 0; reg < 4; reg++) {
                float s = 0.f;
#pragma unroll
                for (int nt = 0; nt < 8; nt++) {
                    float v = acc[mt][nt][reg] + bcol[nt];
                    v = v > 0.f ? v : 0.f;
                    s += v * whc[nt];
                }
                s += __shfl_xor(s, 1);
                s += __shfl_xor(s, 2);
                s += __shfl_xor(s, 4);
                s += __shfl_xor(s, 8);
                int node = nodeBase + reg;
                if (col == 0 && node < n) logits[node] = s + bhv;
            }
        }
    }
}

extern "C" void kernel_launch(void* const* d_in, const int* in_sizes, int n_in,
                              void* d_out, int out_size, void* d_ws, size_t ws_size,
                              hipStream_t stream) {
    const float* x   = (const float*)d_in[0];
    const int*   ei  = (const int*)d_in[1];
    const float* Wn0 = (const float*)d_in[2];
    const float* Wr0 = (const float*)d_in[3];
    const float* b0  = (const float*)d_in[4];
    const float* Wn1 = (const float*)d_in[5];
    const float* Wr1 = (const float*)d_in[6];
    const float* b1  = (const float*)d_in[7];
    const float* Wh  = (const float*)d_in[8];
    const float* bh  = (const float*)d_in[9];
    float* logits = (float*)d_out;

    int N = in_sizes[0] / 128;
    int E = in_sizes[1] / 2;
    const int* src = ei;
    const int* dst = ei + E;

    int nbkt = (N + 63) >> 6;           // 64-node coarse buckets
    int HS = nbkt * NSB;                // histogram entries
    int NB = (HS + 2047) / 2048;        // scan1 blocks
    int chunk = (E + NSB - 1) / NSB;

    char* ws = (char*)d_ws;
    size_t cur = 0;
    auto alloc = [&](size_t bytes) -> void* {
        void* p = ws + cur;
        cur += (bytes + 255) & ~(size_t)255;
        return p;
    };
    int* hist  = (int*)alloc((size_t)HS * 4);
    int* bsums = (int*)alloc((size_t)NB * 4);
    int* bbase = (int*)alloc((size_t)NB * 4);
    int* scrat = (int*)alloc(256);
    int* esrt  = (int*)alloc((size_t)E * 4);
    unsigned short* xb  = (unsigned short*)alloc((size_t)N * 128 * 2);
    unsigned short* h0b = (unsigned short*)alloc((size_t)N * 128 * 2);
    unsigned short* agb = (unsigned short*)alloc((size_t)N * 128 * 2);
    uint4* Wsw0 = (uint4*)alloc(131072);
    uint4* Wsw1 = (uint4*)alloc(131072);
    (void)ws_size; (void)n_in; (void)out_size;

    // precision prep
    int n4 = N * 32;
    hipLaunchKernelGGL(cvt_bf16_kernel, dim3((n4 + 255) / 256), dim3(256), 0, stream,
                       (const float4*)x, (ushort4*)xb, n4);
    hipLaunchKernelGGL(swizzle_w_kernel, dim3(16), dim3(256), 0, stream, Wn0, Wr0, Wsw0);
    hipLaunchKernelGGL(swizzle_w_kernel, dim3(16), dim3(256), 0, stream, Wn1, Wr1, Wsw1);

    // coarse counting sort
    hipLaunchKernelGGL(hist_kernel,    dim3(NSB), dim3(256), 0, stream, dst, hist, E, nbkt, chunk);
    hipLaunchKernelGGL(scan1_kernel,   dim3(NB),  dim3(256), 0, stream, hist, hist, bsums, HS);
    hipLaunchKernelGGL(scan2_kernel,   dim3(1),   dim3(64),  0, stream, bsums, bbase, NB, scrat);
    hipLaunchKernelGGL(scan3b_kernel,  dim3((HS + 255) / 256), dim3(256), 0, stream, hist, bbase, HS);
    hipLaunchKernelGGL(scatter_kernel, dim3(NSB), dim3(256), 0, stream, src, dst, hist, esrt, E, nbkt, chunk);

    int gUpd = (N + 127) / 128;

    // Layer 0
    hipLaunchKernelGGL(agg_fused, dim3(nbkt), dim3(256), 0, stream, xb, hist, esrt, agb, E, nbkt, N);
    hipLaunchKernelGGL((update_mfma<0, false>), dim3(gUpd), dim3(256), 0, stream,
                       agb, (const void*)x, Wsw0, b0, h0b, nullptr, nullptr, nullptr, N);
    // Layer 1 + fused head
    hipLaunchKernelGGL(agg_fused, dim3(nbkt), dim3(256), 0, stream, h0b, hist, esrt, agb, E, nbkt, N);
    hipLaunchKernelGGL((update_mfma<1, true>), dim3(gUpd), dim3(256), 0, stream,
                       agb, (const void*)h0b, Wsw1, b1, nullptr, Wh, bh, logits, N);
}

// Round 7
// 453.159 us; speedup vs baseline: 5.8256x; 5.8256x over previous
//
#include <hip/hip_runtime.h>

#define THREADS 256
#define SCAN_ITEMS 8    // 2048 elements per scan block
#define NSB 64          // sort blocks: run length E/(NSB*nbkt) ~ 16 edges = 64 B
#define BKT_MAX 1600    // >= ceil(N/64)
#define CHUNK 2048      // agg staging chunk (edges)

typedef float f32x4 __attribute__((ext_vector_type(4)));
typedef __bf16 bf16x8 __attribute__((ext_vector_type(8)));

__device__ inline unsigned short f32_to_bf16_rne(float f) {
    unsigned int u = __float_as_uint(f);
    unsigned int r = u + 0x7fffu + ((u >> 16) & 1u);
    return (unsigned short)(r >> 16);
}
__device__ inline float bf16_bits_to_f32(unsigned short h) {
    return __uint_as_float(((unsigned int)h) << 16);
}
__device__ inline uint4 pack8(const unsigned short* s) {
    uint4 u;
    u.x = (unsigned int)s[0] | ((unsigned int)s[1] << 16);
    u.y = (unsigned int)s[2] | ((unsigned int)s[3] << 16);
    u.z = (unsigned int)s[4] | ((unsigned int)s[5] << 16);
    u.w = (unsigned int)s[6] | ((unsigned int)s[7] << 16);
    return u;
}

// ---------------- coarse counting sort (64-node buckets) ----------------
// Pass 1: per-block private LDS histogram -> hist[bucket*NSB + blk]
__global__ __launch_bounds__(256) void hist64(const int* __restrict__ dst,
                                              int* __restrict__ hist,
                                              int E, int nbkt, int chunk) {
    __shared__ int lh[BKT_MAX];
    const int tid = threadIdx.x, blk = blockIdx.x;
    for (int i = tid; i < nbkt; i += 256) lh[i] = 0;
    __syncthreads();
    int s = blk * chunk, e = s + chunk; if (e > E) e = E;
    for (int i = s + tid; i < e; i += 256) atomicAdd(&lh[dst[i] >> 6], 1);
    __syncthreads();
    for (int i = tid; i < nbkt; i += 256) hist[i * NSB + blk] = lh[i];
}

__global__ void scan1_kernel(const int* __restrict__ cnt, int* __restrict__ off,
                             int* __restrict__ bsums, int n) {
    __shared__ int sdata[THREADS];
    int base = blockIdx.x * (THREADS * SCAN_ITEMS) + threadIdx.x * SCAN_ITEMS;
    int vals[SCAN_ITEMS];
    int tsum = 0;
#pragma unroll
    for (int k = 0; k < SCAN_ITEMS; k++) {
        int idx = base + k;
        int v = (idx < n) ? cnt[idx] : 0;
        vals[k] = tsum;
        tsum += v;
    }
    sdata[threadIdx.x] = tsum;
    __syncthreads();
    for (int s = 1; s < THREADS; s <<= 1) {
        int y = (threadIdx.x >= (unsigned)s) ? sdata[threadIdx.x - s] : 0;
        __syncthreads();
        sdata[threadIdx.x] += y;
        __syncthreads();
    }
    int texcl = sdata[threadIdx.x] - tsum;
#pragma unroll
    for (int k = 0; k < SCAN_ITEMS; k++) {
        int idx = base + k;
        if (idx < n) off[idx] = texcl + vals[k];
    }
    if (threadIdx.x == THREADS - 1) bsums[blockIdx.x] = sdata[THREADS - 1];
}

__global__ void scan2_kernel(const int* __restrict__ bsums, int* __restrict__ bbase,
                             int nb, int* __restrict__ offN) {
    if (threadIdx.x == 0 && blockIdx.x == 0) {
        int run = 0;
        for (int i = 0; i < nb; i++) { bbase[i] = run; run += bsums[i]; }
        *offN = run;
    }
}

__global__ void scan3b_kernel(int* __restrict__ off, const int* __restrict__ bbase, int n) {
    int i = blockIdx.x * blockDim.x + threadIdx.x;
    if (i < n) off[i] += bbase[i >> 11];
}

// Pass 2: stable scatter into bucket-grouped array. Each (blk,bucket) run is
// ~16 edges = 64 B, block-private and consecutive -> near-ideal write locality.
// Payload: src (17 bits, N=100k) | dst_local << 17.
__global__ __launch_bounds__(256) void scatter64(const int* __restrict__ src,
                                                 const int* __restrict__ dst,
                                                 const int* __restrict__ hstS,
                                                 int* __restrict__ esrt,
                                                 int E, int nbkt, int chunk) {
    __shared__ int cur[BKT_MAX];
    const int tid = threadIdx.x, blk = blockIdx.x;
    for (int i = tid; i < nbkt; i += 256) cur[i] = hstS[i * NSB + blk];
    __syncthreads();
    int s = blk * chunk, e = s + chunk; if (e > E) e = E;
    for (int i = s + tid; i < e; i += 256) {
        int d = dst[i];
        int p = atomicAdd(&cur[d >> 6], 1);
        esrt[p] = src[i] | ((d & 63) << 17);
    }
}

// ---------------- precision prep ----------------
__global__ void cvt_bf16_kernel(const float4* __restrict__ x, ushort4* __restrict__ o, int n4) {
    int i = blockIdx.x * blockDim.x + threadIdx.x;
    if (i < n4) {
        float4 v = x[i];
        ushort4 r;
        r.x = f32_to_bf16_rne(v.x);
        r.y = f32_to_bf16_rne(v.y);
        r.z = f32_to_bf16_rne(v.z);
        r.w = f32_to_bf16_rne(v.w);
        o[i] = r;
    }
}

// Swizzled hi/lo bf16 weights. W256[k][n]: k<128 -> Wn, else Wr.
// [t(8)][nt(8)][plane(2)][lane(64)] x 16B; B frag: n = lane&15, k = t*32+(lane>>4)*8+j.
__global__ void swizzle_w_kernel(const float* __restrict__ Wn, const float* __restrict__ Wr,
                                 uint4* __restrict__ out) {
    int id = blockIdx.x * blockDim.x + threadIdx.x;
    if (id >= 4096) return;
    int lane = id & 63;
    int nt = (id >> 6) & 7;
    int t = id >> 9;
    int kbase = t * 32 + (lane >> 4) * 8;
    int col = nt * 16 + (lane & 15);
    unsigned short hi[8], lo[8];
#pragma unroll
    for (int j = 0; j < 8; j++) {
        int k = kbase + j;
        const float* W = (k < 128) ? (Wn + (size_t)k * 128) : (Wr + (size_t)(k - 128) * 128);
        float v = W[col];
        unsigned short h = f32_to_bf16_rne(v);
        hi[j] = h;
        lo[j] = f32_to_bf16_rne(v - bf16_bits_to_f32(h));
    }
    out[(size_t)((t * 8 + nt) * 2 + 0) * 64 + lane] = pack8(hi);
    out[(size_t)((t * 8 + nt) * 2 + 1) * 64 + lane] = pack8(lo);
}

// ---------------- bucketed aggregation, register accumulate ----------------
// One block per 64-node bucket. Per 2048-edge chunk: counting-sort by dst&63
// in LDS (few LDS atomics on 64 counters), then wave w walks its 16 nodes'
// contiguous runs, register-accumulating 2 feats/lane (NO per-feature atomics).
__global__ __launch_bounds__(256) void agg_bucket(const unsigned short* __restrict__ hb,
                                                  const int* __restrict__ hstS,
                                                  const int* __restrict__ esrt,
                                                  unsigned short* __restrict__ aggb,
                                                  int E, int nbkt, int n) {
    __shared__ int stage[CHUNK];
    __shared__ int sorted[CHUNK];
    __shared__ int cnt[64];
    __shared__ int coff[65];
    const int tid = threadIdx.x, lane = tid & 63, w = tid >> 6;
    const int b = blockIdx.x;

    float accx[16], accy[16];
    int dcnt[16];
#pragma unroll
    for (int nl = 0; nl < 16; nl++) { accx[nl] = 0.f; accy[nl] = 0.f; dcnt[nl] = 0; }

    const int p0 = hstS[b * NSB];
    const int p1 = (b + 1 < nbkt) ? hstS[(b + 1) * NSB] : E;

    for (int base = p0; base < p1; base += CHUNK) {
        int m = p1 - base; if (m > CHUNK) m = CHUNK;
        for (int i = tid; i < m; i += 256) stage[i] = esrt[base + i];
        if (tid < 64) cnt[tid] = 0;
        __syncthreads();
        for (int i = tid; i < m; i += 256) atomicAdd(&cnt[(stage[i] >> 17) & 63], 1);
        __syncthreads();
        if (tid < 64) {  // wave 0: shfl inclusive scan -> coff, cursor = exclusive
            int v = cnt[tid];
            int x = v;
#pragma unroll
            for (int s = 1; s < 64; s <<= 1) {
                int y = __shfl_up(x, s);
                if (lane >= s) x += y;
            }
            coff[tid + 1] = x;
            if (tid == 0) coff[0] = 0;
            cnt[tid] = x - v;  // run start cursor
        }
        __syncthreads();
        for (int i = tid; i < m; i += 256) {
            int pk = stage[i];
            int p = atomicAdd(&cnt[(pk >> 17) & 63], 1);
            sorted[p] = pk;
        }
        __syncthreads();
        // aggregate: wave w owns nodes w*16 .. w*16+15 (runs are contiguous)
#pragma unroll
        for (int nl = 0; nl < 16; nl++) {
            int node_l = w * 16 + nl;
            int s = coff[node_l], e2 = coff[node_l + 1];
            dcnt[nl] += e2 - s;
            float ax = accx[nl], ay = accy[nl];
            int i = s;
            for (; i + 8 <= e2; i += 8) {
                unsigned int v[8];
#pragma unroll
                for (int j = 0; j < 8; j++) {
                    int sj = sorted[i + j] & 0x1FFFF;  // LDS broadcast read
                    v[j] = *(const unsigned int*)(hb + (size_t)sj * 128 + lane * 2);
                }
#pragma unroll
                for (int j = 0; j < 8; j++) {
                    ax += __uint_as_float(v[j] << 16);
                    ay += __uint_as_float(v[j] & 0xffff0000u);
                }
            }
            for (; i < e2; i++) {
                int sj = sorted[i] & 0x1FFFF;
                unsigned int vv = *(const unsigned int*)(hb + (size_t)sj * 128 + lane * 2);
                ax += __uint_as_float(vv << 16);
                ay += __uint_as_float(vv & 0xffff0000u);
            }
            accx[nl] = ax; accy[nl] = ay;
        }
        __syncthreads();
    }

    // writeout: node = b*64 + w*16 + nl; lane stores its packed dword
#pragma unroll
    for (int nl = 0; nl < 16; nl++) {
        int node = b * 64 + w * 16 + nl;
        if (node < n) {
            int d = dcnt[nl];
            float inv = 1.0f / (float)(d > 1 ? d : 1);
            unsigned int o = (unsigned int)f32_to_bf16_rne(accx[nl] * inv)
                           | ((unsigned int)f32_to_bf16_rne(accy[nl] * inv) << 16);
            *(unsigned int*)(aggb + (size_t)node * 128 + lane * 2) = o;
        }
    }
}

// ---------------- fused SAGE update via split-bf16 MFMA ----------------
template <int LAYER, bool FINAL>
__global__ __launch_bounds__(256, 2) void update_mfma(
    const unsigned short* __restrict__ aggb, const void* __restrict__ hsrc,
    const uint4* __restrict__ Wsw, const float* __restrict__ bias,
    unsigned short* __restrict__ hout,
    const float* __restrict__ Wh, const float* __restrict__ bh,
    float* __restrict__ logits, int n) {
    __shared__ uint4 Alds[2048];
    __shared__ uint4 Wlds[2048];
    const int tid = threadIdx.x;
    const int lane = tid & 63;
    const int w = tid >> 6;
    const int i0 = blockIdx.x * 128;

    f32x4 acc[2][8];
#pragma unroll
    for (int mt = 0; mt < 2; mt++)
#pragma unroll
        for (int nt = 0; nt < 8; nt++) acc[mt][nt] = (f32x4)0.f;

    const int r = tid >> 1;
    const int half = tid & 1;
    const int rg = i0 + r;
    const bool inb = rg < n;
    const int mt_s = r >> 4;
    const int lidx = r & 15;

    for (int c = 0; c < 4; c++) {
        const bool haslo = (LAYER == 0 && c >= 2);
        {
            const uint4* srcW = Wsw + (size_t)c * 2048;
#pragma unroll
            for (int g = 0; g < 8; g++) Wlds[g * 256 + tid] = srcW[g * 256 + tid];
        }
        {
            unsigned short hiA[32], loA[32];
            if (LAYER == 0 && c >= 2) {
                const float4* s4 = (const float4*)((const float*)hsrc + (size_t)rg * 128 +
                                                   (c - 2) * 64 + half * 32);
#pragma unroll
                for (int q = 0; q < 8; q++) {
                    float4 f = inb ? s4[q] : make_float4(0.f, 0.f, 0.f, 0.f);
                    float vv[4] = {f.x, f.y, f.z, f.w};
#pragma unroll
                    for (int e = 0; e < 4; e++) {
                        unsigned short h = f32_to_bf16_rne(vv[e]);
                        hiA[q * 4 + e] = h;
                        loA[q * 4 + e] = f32_to_bf16_rne(vv[e] - bf16_bits_to_f32(h));
                    }
                }
            } else {
                const unsigned short* bsrc = (c < 2) ? aggb : (const unsigned short*)hsrc;
                int cc = (c < 2) ? c : c - 2;
                const uint4* s4 = (const uint4*)(bsrc + (size_t)rg * 128 + cc * 64 + half * 32);
#pragma unroll
                for (int q = 0; q < 4; q++) {
                    uint4 u = inb ? s4[q] : make_uint4(0, 0, 0, 0);
                    unsigned int uu[4] = {u.x, u.y, u.z, u.w};
#pragma unroll
                    for (int e = 0; e < 4; e++) {
                        hiA[q * 8 + e * 2 + 0] = (unsigned short)(uu[e] & 0xffffu);
                        hiA[q * 8 + e * 2 + 1] = (unsigned short)(uu[e] >> 16);
                    }
                }
            }
            unsigned int baseHi = ((mt_s * 2 + half) * 2 + 0) * 64;
#pragma unroll
            for (int g2 = 0; g2 < 4; g2++)
                Alds[baseHi + lidx + 16 * g2] = pack8(&hiA[g2 * 8]);
            if (haslo) {
#pragma unroll
                for (int g2 = 0; g2 < 4; g2++)
                    Alds[baseHi + 64 + lidx + 16 * g2] = pack8(&loA[g2 * 8]);
            }
        }
        __syncthreads();
#pragma unroll
        for (int kt = 0; kt < 2; kt++) {
            bf16x8 a0h = *(const bf16x8*)&Alds[(((w * 2 + 0) * 2 + kt) * 2 + 0) * 64 + lane];
            bf16x8 a1h = *(const bf16x8*)&Alds[(((w * 2 + 1) * 2 + kt) * 2 + 0) * 64 + lane];
            bf16x8 a0l, a1l;
            if (haslo) {
                a0l = *(const bf16x8*)&Alds[(((w * 2 + 0) * 2 + kt) * 2 + 1) * 64 + lane];
                a1l = *(const bf16x8*)&Alds[(((w * 2 + 1) * 2 + kt) * 2 + 1) * 64 + lane];
            }
#pragma unroll
            for (int nt = 0; nt < 8; nt++) {
                bf16x8 bhv = *(const bf16x8*)&Wlds[((kt * 8 + nt) * 2 + 0) * 64 + lane];
                bf16x8 blv = *(const bf16x8*)&Wlds[((kt * 8 + nt) * 2 + 1) * 64 + lane];
                acc[0][nt] = __builtin_amdgcn_mfma_f32_16x16x32_bf16(a0h, bhv, acc[0][nt], 0, 0, 0);
                acc[0][nt] = __builtin_amdgcn_mfma_f32_16x16x32_bf16(a0h, blv, acc[0][nt], 0, 0, 0);
                acc[1][nt] = __builtin_amdgcn_mfma_f32_16x16x32_bf16(a1h, bhv, acc[1][nt], 0, 0, 0);
                acc[1][nt] = __builtin_amdgcn_mfma_f32_16x16x32_bf16(a1h, blv, acc[1][nt], 0, 0, 0);
                if (haslo) {
                    acc[0][nt] = __builtin_amdgcn_mfma_f32_16x16x32_bf16(a0l, bhv, acc[0][nt], 0, 0, 0);
                    acc[1][nt] = __builtin_amdgcn_mfma_f32_16x16x32_bf16(a1l, bhv, acc[1][nt], 0, 0, 0);
                }
            }
        }
        __syncthreads();
    }

    const int col = lane & 15;
    const int g4 = lane >> 4;
    float bcol[8];
#pragma unroll
    for (int nt = 0; nt < 8; nt++) bcol[nt] = bias[nt * 16 + col];
    if (!FINAL) {
#pragma unroll
        for (int mt = 0; mt < 2; mt++) {
            int nodeBase = i0 + (w * 2 + mt) * 16 + g4 * 4;
#pragma unroll
            for (int reg = 0; reg < 4; reg++) {
                int node = nodeBase + reg;
                if (node < n) {
#pragma unroll
                    for (int nt = 0; nt < 8; nt++) {
                        float v = acc[mt][nt][reg] + bcol[nt];
                        v = v > 0.f ? v : 0.f;
                        hout[(size_t)node * 128 + nt * 16 + col] = f32_to_bf16_rne(v);
                    }
                }
            }
        }
    } else {
        float whc[8];
#pragma unroll
        for (int nt = 0; nt < 8; nt++) whc[nt] = Wh[nt * 16 + col];
        float bhv = bh[0];
#pragma unroll
        for (int mt = 0; mt < 2; mt++) {
            int nodeBase = i0 + (w * 2 + mt) * 16 + g4 * 4;
#pragma unroll
            for (int reg = 0; reg < 4; reg++) {
                float s = 0.f;
#pragma unroll
                for (int nt = 0; nt < 8; nt++) {
                    float v = acc[mt][nt][reg] + bcol[nt];
                    v = v > 0.f ? v : 0.f;
                    s += v * whc[nt];
                }
                s += __shfl_xor(s, 1);
                s += __shfl_xor(s, 2);
                s += __shfl_xor(s, 4);
                s += __shfl_xor(s, 8);
                int node = nodeBase + reg;
                if (col == 0 && node < n) logits[node] = s + bhv;
            }
        }
    }
}

extern "C" void kernel_launch(void* const* d_in, const int* in_sizes, int n_in,
                              void* d_out, int out_size, void* d_ws, size_t ws_size,
                              hipStream_t stream) {
    const float* x   = (const float*)d_in[0];
    const int*   ei  = (const int*)d_in[1];
    const float* Wn0 = (const float*)d_in[2];
    const float* Wr0 = (const float*)d_in[3];
    const float* b0  = (const float*)d_in[4];
    const float* Wn1 = (const float*)d_in[5];
    const float* Wr1 = (const float*)d_in[6];
    const float* b1  = (const float*)d_in[7];
    const float* Wh  = (const float*)d_in[8];
    const float* bh  = (const float*)d_in[9];
    float* logits = (float*)d_out;

    int N = in_sizes[0] / 128;
    int E = in_sizes[1] / 2;
    const int* src = ei;
    const int* dst = ei + E;

    int nbkt = (N + 63) >> 6;           // 64-node coarse buckets
    int HS = nbkt * NSB;                // histogram entries
    int NB = (HS + 2047) / 2048;        // scan1 blocks
    int chunk = (E + NSB - 1) / NSB;

    char* ws = (char*)d_ws;
    size_t cur = 0;
    auto alloc = [&](size_t bytes) -> void* {
        void* p = ws + cur;
        cur += (bytes + 255) & ~(size_t)255;
        return p;
    };
    int* hist  = (int*)alloc((size_t)HS * 4);
    int* bsums = (int*)alloc((size_t)NB * 4);
    int* bbase = (int*)alloc((size_t)NB * 4);
    int* scrat = (int*)alloc(256);
    int* esrt  = (int*)alloc((size_t)E * 4);
    unsigned short* xb  = (unsigned short*)alloc((size_t)N * 128 * 2);
    unsigned short* h0b = (unsigned short*)alloc((size_t)N * 128 * 2);
    unsigned short* agb = (unsigned short*)alloc((size_t)N * 128 * 2);
    uint4* Wsw0 = (uint4*)alloc(131072);
    uint4* Wsw1 = (uint4*)alloc(131072);
    (void)ws_size; (void)n_in; (void)out_size;

    // precision prep
    int n4 = N * 32;
    hipLaunchKernelGGL(cvt_bf16_kernel, dim3((n4 + 255) / 256), dim3(256), 0, stream,
                       (const float4*)x, (ushort4*)xb, n4);
    hipLaunchKernelGGL(swizzle_w_kernel, dim3(16), dim3(256), 0, stream, Wn0, Wr0, Wsw0);
    hipLaunchKernelGGL(swizzle_w_kernel, dim3(16), dim3(256), 0, stream, Wn1, Wr1, Wsw1);

    // coarse counting sort (NSB=64 -> 64 B block-private runs)
    hipLaunchKernelGGL(hist64,        dim3(NSB), dim3(256), 0, stream, dst, hist, E, nbkt, chunk);
    hipLaunchKernelGGL(scan1_kernel,  dim3(NB),  dim3(256), 0, stream, hist, hist, bsums, HS);
    hipLaunchKernelGGL(scan2_kernel,  dim3(1),   dim3(64),  0, stream, bsums, bbase, NB, scrat);
    hipLaunchKernelGGL(scan3b_kernel, dim3((HS + 255) / 256), dim3(256), 0, stream, hist, bbase, HS);
    hipLaunchKernelGGL(scatter64,     dim3(NSB), dim3(256), 0, stream, src, dst, hist, esrt, E, nbkt, chunk);

    int gUpd = (N + 127) / 128;

    // Layer 0
    hipLaunchKernelGGL(agg_bucket, dim3(nbkt), dim3(256), 0, stream, xb, hist, esrt, agb, E, nbkt, N);
    hipLaunchKernelGGL((update_mfma<0, false>), dim3(gUpd), dim3(256), 0, stream,
                       agb, (const void*)x, Wsw0, b0, h0b, nullptr, nullptr, nullptr, N);
    // Layer 1 + fused head
    hipLaunchKernelGGL(agg_bucket, dim3(nbkt), dim3(256), 0, stream, h0b, hist, esrt, agb, E, nbkt, N);
    hipLaunchKernelGGL((update_mfma<1, true>), dim3(gUpd), dim3(256), 0, stream,
                       agb, (const void*)h0b, Wsw1, b1, nullptr, Wh, bh, logits, N);
}

// Round 9
// 400.379 us; speedup vs baseline: 6.5936x; 1.1318x over previous
//
#include <hip/hip_runtime.h>

#define THREADS 256
#define SCAN_ITEMS 8    // 2048 elements per scan block
#define NSB 128         // sort blocks: run length E/(NSB*nbkt) ~ 8 edges = 32 B
#define BKT_MAX 1600    // >= ceil(N/64)
#define CHUNK 2048      // agg staging chunk (edges)

typedef float f32x4 __attribute__((ext_vector_type(4)));
typedef __bf16 bf16x8 __attribute__((ext_vector_type(8)));
typedef int intx4 __attribute__((ext_vector_type(4)));

__device__ inline unsigned short f32_to_bf16_rne(float f) {
    unsigned int u = __float_as_uint(f);
    unsigned int r = u + 0x7fffu + ((u >> 16) & 1u);
    return (unsigned short)(r >> 16);
}
__device__ inline float bf16_bits_to_f32(unsigned short h) {
    return __uint_as_float(((unsigned int)h) << 16);
}
__device__ inline uint4 pack8(const unsigned short* s) {
    uint4 u;
    u.x = (unsigned int)s[0] | ((unsigned int)s[1] << 16);
    u.y = (unsigned int)s[2] | ((unsigned int)s[3] << 16);
    u.z = (unsigned int)s[4] | ((unsigned int)s[5] << 16);
    u.w = (unsigned int)s[6] | ((unsigned int)s[7] << 16);
    return u;
}

// ---------------- coarse counting sort (64-node buckets) ----------------
// Pass 1: per-block private LDS histogram -> hist[bucket*NSB + blk].
// int4 edge reads: 4 independent loads in flight per thread-iteration.
__global__ __launch_bounds__(256) void hist64(const int* __restrict__ dst,
                                              int* __restrict__ hist,
                                              int E, int nbkt, int chunk) {
    __shared__ int lh[BKT_MAX];
    const int tid = threadIdx.x, blk = blockIdx.x;
    for (int i = tid; i < nbkt; i += 256) lh[i] = 0;
    __syncthreads();
    int s = blk * chunk, e = s + chunk; if (e > E) e = E;
    if (((size_t)dst & 15) == 0) {   // chunk%4==0 -> dst+s is 16B aligned
        int n4 = (e > s) ? ((e - s) >> 2) : 0;
        const intx4* d4p = (const intx4*)(dst + s);
        for (int i = tid; i < n4; i += 256) {
            intx4 d4 = d4p[i];
#pragma unroll
            for (int k = 0; k < 4; k++) atomicAdd(&lh[d4[k] >> 6], 1);
        }
        for (int j = s + (n4 << 2) + tid; j < e; j += 256) atomicAdd(&lh[dst[j] >> 6], 1);
    } else {
        for (int j = s + tid; j < e; j += 256) atomicAdd(&lh[dst[j] >> 6], 1);
    }
    __syncthreads();
    for (int i = tid; i < nbkt; i += 256) hist[i * NSB + blk] = lh[i];
}

__global__ void scan1_kernel(const int* __restrict__ cnt, int* __restrict__ off,
                             int* __restrict__ bsums, int n) {
    __shared__ int sdata[THREADS];
    int base = blockIdx.x * (THREADS * SCAN_ITEMS) + threadIdx.x * SCAN_ITEMS;
    int vals[SCAN_ITEMS];
    int tsum = 0;
#pragma unroll
    for (int k = 0; k < SCAN_ITEMS; k++) {
        int idx = base + k;
        int v = (idx < n) ? cnt[idx] : 0;
        vals[k] = tsum;
        tsum += v;
    }
    sdata[threadIdx.x] = tsum;
    __syncthreads();
    for (int s = 1; s < THREADS; s <<= 1) {
        int y = (threadIdx.x >= (unsigned)s) ? sdata[threadIdx.x - s] : 0;
        __syncthreads();
        sdata[threadIdx.x] += y;
        __syncthreads();
    }
    int texcl = sdata[threadIdx.x] - tsum;
#pragma unroll
    for (int k = 0; k < SCAN_ITEMS; k++) {
        int idx = base + k;
        if (idx < n) off[idx] = texcl + vals[k];
    }
    if (threadIdx.x == THREADS - 1) bsums[blockIdx.x] = sdata[THREADS - 1];
}

__global__ void scan2_kernel(const int* __restrict__ bsums, int* __restrict__ bbase,
                             int nb, int* __restrict__ offN) {
    if (threadIdx.x == 0 && blockIdx.x == 0) {
        int run = 0;
        for (int i = 0; i < nb; i++) { bbase[i] = run; run += bsums[i]; }
        *offN = run;
    }
}

__global__ void scan3b_kernel(int* __restrict__ off, const int* __restrict__ bbase, int n) {
    int i = blockIdx.x * blockDim.x + threadIdx.x;
    if (i < n) off[i] += bbase[i >> 11];
}

// Pass 2: stable scatter into bucket-grouped array. Runs ~8 edges = 32 B,
// block-private and consecutive. int4 edge reads for MLP; order within a
// run doesn't matter (sum is commutative). Payload: src | dst_local<<17.
__global__ __launch_bounds__(256) void scatter64(const int* __restrict__ src,
                                                 const int* __restrict__ dst,
                                                 const int* __restrict__ hstS,
                                                 int* __restrict__ esrt,
                                                 int E, int nbkt, int chunk) {
    __shared__ int cur[BKT_MAX];
    const int tid = threadIdx.x, blk = blockIdx.x;
    for (int i = tid; i < nbkt; i += 256) cur[i] = hstS[i * NSB + blk];
    __syncthreads();
    int s = blk * chunk, e = s + chunk; if (e > E) e = E;
    if ((((size_t)dst | (size_t)src) & 15) == 0) {
        int n4 = (e > s) ? ((e - s) >> 2) : 0;
        const intx4* d4p = (const intx4*)(dst + s);
        const intx4* s4p = (const intx4*)(src + s);
        for (int i = tid; i < n4; i += 256) {
            intx4 d4 = d4p[i];
            intx4 s4 = s4p[i];
#pragma unroll
            for (int k = 0; k < 4; k++) {
                int d = d4[k];
                int p = atomicAdd(&cur[d >> 6], 1);
                esrt[p] = s4[k] | ((d & 63) << 17);
            }
        }
        for (int j = s + (n4 << 2) + tid; j < e; j += 256) {
            int d = dst[j];
            int p = atomicAdd(&cur[d >> 6], 1);
            esrt[p] = src[j] | ((d & 63) << 17);
        }
    } else {
        for (int j = s + tid; j < e; j += 256) {
            int d = dst[j];
            int p = atomicAdd(&cur[d >> 6], 1);
            esrt[p] = src[j] | ((d & 63) << 17);
        }
    }
}

// ---------------- precision prep ----------------
__global__ void cvt_bf16_kernel(const float4* __restrict__ x, ushort4* __restrict__ o, int n4) {
    int i = blockIdx.x * blockDim.x + threadIdx.x;
    if (i < n4) {
        float4 v = x[i];
        ushort4 r;
        r.x = f32_to_bf16_rne(v.x);
        r.y = f32_to_bf16_rne(v.y);
        r.z = f32_to_bf16_rne(v.z);
        r.w = f32_to_bf16_rne(v.w);
        o[i] = r;
    }
}

// Swizzled hi/lo bf16 weights. W256[k][n]: k<128 -> Wn, else Wr.
// [t(8)][nt(8)][plane(2)][lane(64)] x 16B; B frag: n = lane&15, k = t*32+(lane>>4)*8+j.
__global__ void swizzle_w_kernel(const float* __restrict__ Wn, const float* __restrict__ Wr,
                                 uint4* __restrict__ out) {
    int id = blockIdx.x * blockDim.x + threadIdx.x;
    if (id >= 4096) return;
    int lane = id & 63;
    int nt = (id >> 6) & 7;
    int t = id >> 9;
    int kbase = t * 32 + (lane >> 4) * 8;
    int col = nt * 16 + (lane & 15);
    unsigned short hi[8], lo[8];
#pragma unroll
    for (int j = 0; j < 8; j++) {
        int k = kbase + j;
        const float* W = (k < 128) ? (Wn + (size_t)k * 128) : (Wr + (size_t)(k - 128) * 128);
        float v = W[col];
        unsigned short h = f32_to_bf16_rne(v);
        hi[j] = h;
        lo[j] = f32_to_bf16_rne(v - bf16_bits_to_f32(h));
    }
    out[(size_t)((t * 8 + nt) * 2 + 0) * 64 + lane] = pack8(hi);
    out[(size_t)((t * 8 + nt) * 2 + 1) * 64 + lane] = pack8(lo);
}

// ---------------- bucketed aggregation, register accumulate ----------------
__global__ __launch_bounds__(256) void agg_bucket(const unsigned short* __restrict__ hb,
                                                  const int* __restrict__ hstS,
                                                  const int* __restrict__ esrt,
                                                  unsigned short* __restrict__ aggb,
                                                  int E, int nbkt, int n) {
    __shared__ int stage[CHUNK];
    __shared__ int sorted[CHUNK];
    __shared__ int cnt[64];
    __shared__ int coff[65];
    const int tid = threadIdx.x, lane = tid & 63, w = tid >> 6;
    const int b = blockIdx.x;

    float accx[16], accy[16];
    int dcnt[16];
#pragma unroll
    for (int nl = 0; nl < 16; nl++) { accx[nl] = 0.f; accy[nl] = 0.f; dcnt[nl] = 0; }

    const int p0 = hstS[b * NSB];
    const int p1 = (b + 1 < nbkt) ? hstS[(b + 1) * NSB] : E;

    for (int base = p0; base < p1; base += CHUNK) {
        int m = p1 - base; if (m > CHUNK) m = CHUNK;
        for (int i = tid; i < m; i += 256) stage[i] = esrt[base + i];
        if (tid < 64) cnt[tid] = 0;
        __syncthreads();
        for (int i = tid; i < m; i += 256) atomicAdd(&cnt[(stage[i] >> 17) & 63], 1);
        __syncthreads();
        if (tid < 64) {  // wave 0: shfl inclusive scan -> coff, cursor = exclusive
            int v = cnt[tid];
            int x = v;
#pragma unroll
            for (int s = 1; s < 64; s <<= 1) {
                int y = __shfl_up(x, s);
                if (lane >= s) x += y;
            }
            coff[tid + 1] = x;
            if (tid == 0) coff[0] = 0;
            cnt[tid] = x - v;  // run start cursor
        }
        __syncthreads();
        for (int i = tid; i < m; i += 256) {
            int pk = stage[i];
            int p = atomicAdd(&cnt[(pk >> 17) & 63], 1);
            sorted[p] = pk;
        }
        __syncthreads();
#pragma unroll
        for (int nl = 0; nl < 16; nl++) {
            int node_l = w * 16 + nl;
            int s = coff[node_l], e2 = coff[node_l + 1];
            dcnt[nl] += e2 - s;
            float ax = accx[nl], ay = accy[nl];
            int i = s;
            for (; i + 8 <= e2; i += 8) {
                unsigned int v[8];
#pragma unroll
                for (int j = 0; j < 8; j++) {
                    int sj = sorted[i + j] & 0x1FFFF;  // LDS broadcast read
                    v[j] = *(const unsigned int*)(hb + (size_t)sj * 128 + lane * 2);
                }
#pragma unroll
                for (int j = 0; j < 8; j++) {
                    ax += __uint_as_float(v[j] << 16);
                    ay += __uint_as_float(v[j] & 0xffff0000u);
                }
            }
            for (; i < e2; i++) {
                int sj = sorted[i] & 0x1FFFF;
                unsigned int vv = *(const unsigned int*)(hb + (size_t)sj * 128 + lane * 2);
                ax += __uint_as_float(vv << 16);
                ay += __uint_as_float(vv & 0xffff0000u);
            }
            accx[nl] = ax; accy[nl] = ay;
        }
        __syncthreads();
    }

#pragma unroll
    for (int nl = 0; nl < 16; nl++) {
        int node = b * 64 + w * 16 + nl;
        if (node < n) {
            int d = dcnt[nl];
            float inv = 1.0f / (float)(d > 1 ? d : 1);
            unsigned int o = (unsigned int)f32_to_bf16_rne(accx[nl] * inv)
                           | ((unsigned int)f32_to_bf16_rne(accy[nl] * inv) << 16);
            *(unsigned int*)(aggb + (size_t)node * 128 + lane * 2) = o;
        }
    }
}

// ---------------- fused SAGE update via split-bf16 MFMA ----------------
template <int LAYER, bool FINAL>
__global__ __launch_bounds__(256, 2) void update_mfma(
    const unsigned short* __restrict__ aggb, const void* __restrict__ hsrc,
    const uint4* __restrict__ Wsw, const float* __restrict__ bias,
    unsigned short* __restrict__ hout,
    const float* __restrict__ Wh, const float* __restrict__ bh,
    float* __restrict__ logits, int n) {
    __shared__ uint4 Alds[2048];
    __shared__ uint4 Wlds[2048];
    const int tid = threadIdx.x;
    const int lane = tid & 63;
    const int w = tid >> 6;
    const int i0 = blockIdx.x * 128;

    f32x4 acc[2][8];
#pragma unroll
    for (int mt = 0; mt < 2; mt++)
#pragma unroll
        for (int nt = 0; nt < 8; nt++) acc[mt][nt] = (f32x4)0.f;

    const int r = tid >> 1;
    const int half = tid & 1;
    const int rg = i0 + r;
    const bool inb = rg < n;
    const int mt_s = r >> 4;
    const int lidx = r & 15;

    for (int c = 0; c < 4; c++) {
        const bool haslo = (LAYER == 0 && c >= 2);
        {
            const uint4* srcW = Wsw + (size_t)c * 2048;
#pragma unroll
            for (int g = 0; g < 8; g++) Wlds[g * 256 + tid] = srcW[g * 256 + tid];
        }
        {
            unsigned short hiA[32], loA[32];
            if (LAYER == 0 && c >= 2) {
                const float4* s4 = (const float4*)((const float*)hsrc + (size_t)rg * 128 +
                                                   (c - 2) * 64 + half * 32);
#pragma unroll
                for (int q = 0; q < 8; q++) {
                    float4 f = inb ? s4[q] : make_float4(0.f, 0.f, 0.f, 0.f);
                    float vv[4] = {f.x, f.y, f.z, f.w};
#pragma unroll
                    for (int e = 0; e < 4; e++) {
                        unsigned short h = f32_to_bf16_rne(vv[e]);
                        hiA[q * 4 + e] = h;
                        loA[q * 4 + e] = f32_to_bf16_rne(vv[e] - bf16_bits_to_f32(h));
                    }
                }
            } else {
                const unsigned short* bsrc = (c < 2) ? aggb : (const unsigned short*)hsrc;
                int cc = (c < 2) ? c : c - 2;
                const uint4* s4 = (const uint4*)(bsrc + (size_t)rg * 128 + cc * 64 + half * 32);
#pragma unroll
                for (int q = 0; q < 4; q++) {
                    uint4 u = inb ? s4[q] : make_uint4(0, 0, 0, 0);
                    unsigned int uu[4] = {u.x, u.y, u.z, u.w};
#pragma unroll
                    for (int e = 0; e < 4; e++) {
                        hiA[q * 8 + e * 2 + 0] = (unsigned short)(uu[e] & 0xffffu);
                        hiA[q * 8 + e * 2 + 1] = (unsigned short)(uu[e] >> 16);
                    }
                }
            }
            unsigned int baseHi = ((mt_s * 2 + half) * 2 + 0) * 64;
#pragma unroll
            for (int g2 = 0; g2 < 4; g2++)
                Alds[baseHi + lidx + 16 * g2] = pack8(&hiA[g2 * 8]);
            if (haslo) {
#pragma unroll
                for (int g2 = 0; g2 < 4; g2++)
                    Alds[baseHi + 64 + lidx + 16 * g2] = pack8(&loA[g2 * 8]);
            }
        }
        __syncthreads();
#pragma unroll
        for (int kt = 0; kt < 2; kt++) {
            bf16x8 a0h = *(const bf16x8*)&Alds[(((w * 2 + 0) * 2 + kt) * 2 + 0) * 64 + lane];
            bf16x8 a1h = *(const bf16x8*)&Alds[(((w * 2 + 1) * 2 + kt) * 2 + 0) * 64 + lane];
            bf16x8 a0l, a1l;
            if (haslo) {
                a0l = *(const bf16x8*)&Alds[(((w * 2 + 0) * 2 + kt) * 2 + 1) * 64 + lane];
                a1l = *(const bf16x8*)&Alds[(((w * 2 + 1) * 2 + kt) * 2 + 1) * 64 + lane];
            }
#pragma unroll
            for (int nt = 0; nt < 8; nt++) {
                bf16x8 bhv = *(const bf16x8*)&Wlds[((kt * 8 + nt) * 2 + 0) * 64 + lane];
                bf16x8 blv = *(const bf16x8*)&Wlds[((kt * 8 + nt) * 2 + 1) * 64 + lane];
                acc[0][nt] = __builtin_amdgcn_mfma_f32_16x16x32_bf16(a0h, bhv, acc[0][nt], 0, 0, 0);
                acc[0][nt] = __builtin_amdgcn_mfma_f32_16x16x32_bf16(a0h, blv, acc[0][nt], 0, 0, 0);
                acc[1][nt] = __builtin_amdgcn_mfma_f32_16x16x32_bf16(a1h, bhv, acc[1][nt], 0, 0, 0);
                acc[1][nt] = __builtin_amdgcn_mfma_f32_16x16x32_bf16(a1h, blv, acc[1][nt], 0, 0, 0);
                if (haslo) {
                    acc[0][nt] = __builtin_amdgcn_mfma_f32_16x16x32_bf16(a0l, bhv, acc[0][nt], 0, 0, 0);
                    acc[1][nt] = __builtin_amdgcn_mfma_f32_16x16x32_bf16(a1l, bhv, acc[1][nt], 0, 0, 0);
                }
            }
        }
        __syncthreads();
    }

    const int col = lane & 15;
    const int g4 = lane >> 4;
    float bcol[8];
#pragma unroll
    for (int nt = 0; nt < 8; nt++) bcol[nt] = bias[nt * 16 + col];
    if (!FINAL) {
#pragma unroll
        for (int mt = 0; mt < 2; mt++) {
            int nodeBase = i0 + (w * 2 + mt) * 16 + g4 * 4;
#pragma unroll
            for (int reg = 0; reg < 4; reg++) {
                int node = nodeBase + reg;
                if (node < n) {
#pragma unroll
                    for (int nt = 0; nt < 8; nt++) {
                        float v = acc[mt][nt][reg] + bcol[nt];
                        v = v > 0.f ? v : 0.f;
                        hout[(size_t)node * 128 + nt * 16 + col] = f32_to_bf16_rne(v);
                    }
                }
            }
        }
    } else {
        float whc[8];
#pragma unroll
        for (int nt = 0; nt < 8; nt++) whc[nt] = Wh[nt * 16 + col];
        float bhv = bh[0];
#pragma unroll
        for (int mt = 0; mt < 2; mt++) {
            int nodeBase = i0 + (w * 2 + mt) * 16 + g4 * 4;
#pragma unroll
            for (int reg = 0; reg < 4; reg++) {
                float s = 0.f;
#pragma unroll
                for (int nt = 0; nt < 8; nt++) {
                    float v = acc[mt][nt][reg] + bcol[nt];
                    v = v > 0.f ? v : 0.f;
                    s += v * whc[nt];
                }
                s += __shfl_xor(s, 1);
                s += __shfl_xor(s, 2);
                s += __shfl_xor(s, 4);
                s += __shfl_xor(s, 8);
                int node = nodeBase + reg;
                if (col == 0 && node < n) logits[node] = s + bhv;
            }
        }
    }
}

extern "C" void kernel_launch(void* const* d_in, const int* in_sizes, int n_in,
                              void* d_out, int out_size, void* d_ws, size_t ws_size,
                              hipStream_t stream) {
    const float* x   = (const float*)d_in[0];
    const int*   ei  = (const int*)d_in[1];
    const float* Wn0 = (const float*)d_in[2];
    const float* Wr0 = (const float*)d_in[3];
    const float* b0  = (const float*)d_in[4];
    const float* Wn1 = (const float*)d_in[5];
    const float* Wr1 = (const float*)d_in[6];
    const float* b1  = (const float*)d_in[7];
    const float* Wh  = (const float*)d_in[8];
    const float* bh  = (const float*)d_in[9];
    float* logits = (float*)d_out;

    int N = in_sizes[0] / 128;
    int E = in_sizes[1] / 2;
    const int* src = ei;
    const int* dst = ei + E;

    int nbkt = (N + 63) >> 6;                       // 64-node coarse buckets
    int HS = nbkt * NSB;                            // histogram entries
    int NB = (HS + 2047) / 2048;                    // scan1 blocks
    int chunk = (((E + NSB - 1) / NSB) + 3) & ~3;   // multiple of 4 for int4 path

    char* ws = (char*)d_ws;
    size_t cur = 0;
    auto alloc = [&](size_t bytes) -> void* {
        void* p = ws + cur;
        cur += (bytes + 255) & ~(size_t)255;
        return p;
    };
    int* hist  = (int*)alloc((size_t)HS * 4);
    int* bsums = (int*)alloc((size_t)NB * 4);
    int* bbase = (int*)alloc((size_t)NB * 4);
    int* scrat = (int*)alloc(256);
    int* esrt  = (int*)alloc((size_t)E * 4);
    unsigned short* xb  = (unsigned short*)alloc((size_t)N * 128 * 2);
    unsigned short* h0b = (unsigned short*)alloc((size_t)N * 128 * 2);
    unsigned short* agb = (unsigned short*)alloc((size_t)N * 128 * 2);
    uint4* Wsw0 = (uint4*)alloc(131072);
    uint4* Wsw1 = (uint4*)alloc(131072);
    (void)ws_size; (void)n_in; (void)out_size;

    // precision prep
    int n4 = N * 32;
    hipLaunchKernelGGL(cvt_bf16_kernel, dim3((n4 + 255) / 256), dim3(256), 0, stream,
                       (const float4*)x, (ushort4*)xb, n4);
    hipLaunchKernelGGL(swizzle_w_kernel, dim3(16), dim3(256), 0, stream, Wn0, Wr0, Wsw0);
    hipLaunchKernelGGL(swizzle_w_kernel, dim3(16), dim3(256), 0, stream, Wn1, Wr1, Wsw1);

    // coarse counting sort (NSB=128, int4 edge reads)
    hipLaunchKernelGGL(hist64,        dim3(NSB), dim3(256), 0, stream, dst, hist, E, nbkt, chunk);
    hipLaunchKernelGGL(scan1_kernel,  dim3(NB),  dim3(256), 0, stream, hist, hist, bsums, HS);
    hipLaunchKernelGGL(scan2_kernel,  dim3(1),   dim3(64),  0, stream, bsums, bbase, NB, scrat);
    hipLaunchKernelGGL(scan3b_kernel, dim3((HS + 255) / 256), dim3(256), 0, stream, hist, bbase, HS);
    hipLaunchKernelGGL(scatter64,     dim3(NSB), dim3(256), 0, stream, src, dst, hist, esrt, E, nbkt, chunk);

    int gUpd = (N + 127) / 128;

    // Layer 0
    hipLaunchKernelGGL(agg_bucket, dim3(nbkt), dim3(256), 0, stream, xb, hist, esrt, agb, E, nbkt, N);
    hipLaunchKernelGGL((update_mfma<0, false>), dim3(gUpd), dim3(256), 0, stream,
                       agb, (const void*)x, Wsw0, b0, h0b, nullptr, nullptr, nullptr, N);
    // Layer 1 + fused head
    hipLaunchKernelGGL(agg_bucket, dim3(nbkt), dim3(256), 0, stream, h0b, hist, esrt, agb, E, nbkt, N);
    hipLaunchKernelGGL((update_mfma<1, true>), dim3(gUpd), dim3(256), 0, stream,
                       agb, (const void*)h0b, Wsw1, b1, nullptr, Wh, bh, logits, N);
}

// Round 12
// 373.316 us; speedup vs baseline: 7.0716x; 1.0725x over previous
//
#include <hip/hip_runtime.h>

#define THREADS 256
#define SCAN_ITEMS 8    // 2048 elements per scan block
#define NSB 128         // sort blocks: run length E/(NSB*nbkt) ~ 8 edges = 32 B
#define BKT_MAX 1600    // >= ceil(N/64)
#define CHUNK 2048      // agg staging chunk (edges)

typedef float f32x4 __attribute__((ext_vector_type(4)));
typedef __bf16 bf16x8 __attribute__((ext_vector_type(8)));
typedef int intx4 __attribute__((ext_vector_type(4)));

__device__ inline unsigned short f32_to_bf16_rne(float f) {
    unsigned int u = __float_as_uint(f);
    unsigned int r = u + 0x7fffu + ((u >> 16) & 1u);
    return (unsigned short)(r >> 16);
}
__device__ inline float bf16_bits_to_f32(unsigned short h) {
    return __uint_as_float(((unsigned int)h) << 16);
}
__device__ inline uint4 pack8(const unsigned short* s) {
    uint4 u;
    u.x = (unsigned int)s[0] | ((unsigned int)s[1] << 16);
    u.y = (unsigned int)s[2] | ((unsigned int)s[3] << 16);
    u.z = (unsigned int)s[4] | ((unsigned int)s[5] << 16);
    u.w = (unsigned int)s[6] | ((unsigned int)s[7] << 16);
    return u;
}

// ---------------- coarse counting sort (64-node buckets) ----------------
__global__ __launch_bounds__(256) void hist64(const int* __restrict__ dst,
                                              int* __restrict__ hist,
                                              int E, int nbkt, int chunk) {
    __shared__ int lh[BKT_MAX];
    const int tid = threadIdx.x, blk = blockIdx.x;
    for (int i = tid; i < nbkt; i += 256) lh[i] = 0;
    __syncthreads();
    int s = blk * chunk, e = s + chunk; if (e > E) e = E;
    if (((size_t)dst & 15) == 0) {
        int n4 = (e > s) ? ((e - s) >> 2) : 0;
        const intx4* d4p = (const intx4*)(dst + s);
        for (int i = tid; i < n4; i += 256) {
            intx4 d4 = d4p[i];
#pragma unroll
            for (int k = 0; k < 4; k++) atomicAdd(&lh[d4[k] >> 6], 1);
        }
        for (int j = s + (n4 << 2) + tid; j < e; j += 256) atomicAdd(&lh[dst[j] >> 6], 1);
    } else {
        for (int j = s + tid; j < e; j += 256) atomicAdd(&lh[dst[j] >> 6], 1);
    }
    __syncthreads();
    for (int i = tid; i < nbkt; i += 256) hist[i * NSB + blk] = lh[i];
}

__global__ void scan1_kernel(const int* __restrict__ cnt, int* __restrict__ off,
                             int* __restrict__ bsums, int n) {
    __shared__ int sdata[THREADS];
    int base = blockIdx.x * (THREADS * SCAN_ITEMS) + threadIdx.x * SCAN_ITEMS;
    int vals[SCAN_ITEMS];
    int tsum = 0;
#pragma unroll
    for (int k = 0; k < SCAN_ITEMS; k++) {
        int idx = base + k;
        int v = (idx < n) ? cnt[idx] : 0;
        vals[k] = tsum;
        tsum += v;
    }
    sdata[threadIdx.x] = tsum;
    __syncthreads();
    for (int s = 1; s < THREADS; s <<= 1) {
        int y = (threadIdx.x >= (unsigned)s) ? sdata[threadIdx.x - s] : 0;
        __syncthreads();
        sdata[threadIdx.x] += y;
        __syncthreads();
    }
    int texcl = sdata[threadIdx.x] - tsum;
#pragma unroll
    for (int k = 0; k < SCAN_ITEMS; k++) {
        int idx = base + k;
        if (idx < n) off[idx] = texcl + vals[k];
    }
    if (threadIdx.x == THREADS - 1) bsums[blockIdx.x] = sdata[THREADS - 1];
}

__global__ void scan2_kernel(const int* __restrict__ bsums, int* __restrict__ bbase,
                             int nb, int* __restrict__ offN) {
    if (threadIdx.x == 0 && blockIdx.x == 0) {
        int run = 0;
        for (int i = 0; i < nb; i++) { bbase[i] = run; run += bsums[i]; }
        *offN = run;
    }
}

__global__ void scan3b_kernel(int* __restrict__ off, const int* __restrict__ bbase, int n) {
    int i = blockIdx.x * blockDim.x + threadIdx.x;
    if (i < n) off[i] += bbase[i >> 11];
}

// Pass 2: stable scatter into bucket-grouped array. Payload: src | dst_local<<17.
__global__ __launch_bounds__(256) void scatter64(const int* __restrict__ src,
                                                 const int* __restrict__ dst,
                                                 const int* __restrict__ hstS,
                                                 int* __restrict__ esrt,
                                                 int E, int nbkt, int chunk) {
    __shared__ int cur[BKT_MAX];
    const int tid = threadIdx.x, blk = blockIdx.x;
    for (int i = tid; i < nbkt; i += 256) cur[i] = hstS[i * NSB + blk];
    __syncthreads();
    int s = blk * chunk, e = s + chunk; if (e > E) e = E;
    if ((((size_t)dst | (size_t)src) & 15) == 0) {
        int n4 = (e > s) ? ((e - s) >> 2) : 0;
        const intx4* d4p = (const intx4*)(dst + s);
        const intx4* s4p = (const intx4*)(src + s);
        for (int i = tid; i < n4; i += 256) {
            intx4 d4 = d4p[i];
            intx4 s4 = s4p[i];
#pragma unroll
            for (int k = 0; k < 4; k++) {
                int d = d4[k];
                int p = atomicAdd(&cur[d >> 6], 1);
                esrt[p] = s4[k] | ((d & 63) << 17);
            }
        }
        for (int j = s + (n4 << 2) + tid; j < e; j += 256) {
            int d = dst[j];
            int p = atomicAdd(&cur[d >> 6], 1);
            esrt[p] = src[j] | ((d & 63) << 17);
        }
    } else {
        for (int j = s + tid; j < e; j += 256) {
            int d = dst[j];
            int p = atomicAdd(&cur[d >> 6], 1);
            esrt[p] = src[j] | ((d & 63) << 17);
        }
    }
}

// ---------------- precision prep ----------------
__global__ void cvt_bf16_kernel(const float4* __restrict__ x, ushort4* __restrict__ o, int n4) {
    int i = blockIdx.x * blockDim.x + threadIdx.x;
    if (i < n4) {
        float4 v = x[i];
        ushort4 r;
        r.x = f32_to_bf16_rne(v.x);
        r.y = f32_to_bf16_rne(v.y);
        r.z = f32_to_bf16_rne(v.z);
        r.w = f32_to_bf16_rne(v.w);
        o[i] = r;
    }
}

// Swizzled hi/lo bf16 weights. W256[k][n]: k<128 -> Wn, else Wr.
__global__ void swizzle_w_kernel(const float* __restrict__ Wn, const float* __restrict__ Wr,
                                 uint4* __restrict__ out) {
    int id = blockIdx.x * blockDim.x + threadIdx.x;
    if (id >= 4096) return;
    int lane = id & 63;
    int nt = (id >> 6) & 7;
    int t = id >> 9;
    int kbase = t * 32 + (lane >> 4) * 8;
    int col = nt * 16 + (lane & 15);
    unsigned short hi[8], lo[8];
#pragma unroll
    for (int j = 0; j < 8; j++) {
        int k = kbase + j;
        const float* W = (k < 128) ? (Wn + (size_t)k * 128) : (Wr + (size_t)(k - 128) * 128);
        float v = W[col];
        unsigned short h = f32_to_bf16_rne(v);
        hi[j] = h;
        lo[j] = f32_to_bf16_rne(v - bf16_bits_to_f32(h));
    }
    out[(size_t)((t * 8 + nt) * 2 + 0) * 64 + lane] = pack8(hi);
    out[(size_t)((t * 8 + nt) * 2 + 1) * 64 + lane] = pack8(lo);
}

// ---------------- bucketed aggregation, flat 8-deep gather ----------------
// Fast path (bucket fits one chunk): LDS counting-sort, then wave w walks its
// 16 nodes' CONTIGUOUS edge range in flat 8-edge batches (8 independent row
// loads always in flight, no per-node drain). Flush loops bounded. Fallback:
// R9 static-register per-node path for multi-chunk buckets.
__global__ __launch_bounds__(256) void agg_bucket(const unsigned short* __restrict__ hb,
                                                  const int* __restrict__ hstS,
                                                  const int* __restrict__ esrt,
                                                  unsigned short* __restrict__ aggb,
                                                  int E, int nbkt, int n) {
    __shared__ int stage[CHUNK];
    __shared__ int sorted[CHUNK];
    __shared__ int cnt[64];
    __shared__ int coff[65];
    const int tid = threadIdx.x, lane = tid & 63, w = tid >> 6;
    const int b = blockIdx.x;

    const int p0 = hstS[b * NSB];
    const int p1 = (b + 1 < nbkt) ? hstS[(b + 1) * NSB] : E;

    if (p1 - p0 <= CHUNK) {
        // ---- sort chunk into LDS ----
        int m = p1 - p0;
        for (int i = tid; i < m; i += 256) stage[i] = esrt[p0 + i];
        if (tid < 64) cnt[tid] = 0;
        __syncthreads();
        for (int i = tid; i < m; i += 256) atomicAdd(&cnt[(stage[i] >> 17) & 63], 1);
        __syncthreads();
        if (tid < 64) {
            int v = cnt[tid];
            int x = v;
#pragma unroll
            for (int s = 1; s < 64; s <<= 1) {
                int y = __shfl_up(x, s);
                if (lane >= s) x += y;
            }
            coff[tid + 1] = x;
            if (tid == 0) coff[0] = 0;
            cnt[tid] = x - v;
        }
        __syncthreads();
        for (int i = tid; i < m; i += 256) {
            int pk = stage[i];
            int p = atomicAdd(&cnt[(pk >> 17) & 63], 1);
            sorted[p] = pk;
        }
        __syncthreads();
        // ---- flat gather: wave w covers edges [coff[16w], coff[16w+16]) ----
        const int nodeEnd = w * 16 + 16;
        int cur = w * 16;
        int s = coff[cur], e2 = coff[nodeEnd];
        float ax = 0.f, ay = 0.f;
        int i = s;
        for (; i + 8 <= e2; i += 8) {
            unsigned int v[8];
            int nd[8];
#pragma unroll
            for (int j = 0; j < 8; j++) {
                int pk = sorted[i + j];           // broadcast LDS read
                nd[j] = (pk >> 17) & 63;          // wave-uniform
                v[j] = *(const unsigned int*)(hb + (size_t)(pk & 0x1FFFF) * 128 + lane * 2);
            }
#pragma unroll
            for (int j = 0; j < 8; j++) {
                while (cur < nd[j]) {             // flush finished node(s), bounded
                    int node = b * 64 + cur;
                    int d = coff[cur + 1] - coff[cur];
                    float inv = 1.0f / (float)(d > 1 ? d : 1);
                    unsigned int o = (unsigned int)f32_to_bf16_rne(ax * inv)
                                   | ((unsigned int)f32_to_bf16_rne(ay * inv) << 16);
                    if (node < n)
                        *(unsigned int*)(aggb + (size_t)node * 128 + lane * 2) = o;
                    ax = 0.f; ay = 0.f; cur++;
                }
                ax += __uint_as_float(v[j] << 16);
                ay += __uint_as_float(v[j] & 0xffff0000u);
            }
        }
        for (; i < e2; i++) {
            int pk = sorted[i];
            int nd = (pk >> 17) & 63;
            unsigned int vv = *(const unsigned int*)(hb + (size_t)(pk & 0x1FFFF) * 128 + lane * 2);
            while (cur < nd) {                    // bounded flush
                int node = b * 64 + cur;
                int d = coff[cur + 1] - coff[cur];
                float inv = 1.0f / (float)(d > 1 ? d : 1);
                unsigned int o = (unsigned int)f32_to_bf16_rne(ax * inv)
                               | ((unsigned int)f32_to_bf16_rne(ay * inv) << 16);
                if (node < n)
                    *(unsigned int*)(aggb + (size_t)node * 128 + lane * 2) = o;
                ax = 0.f; ay = 0.f; cur++;
            }
            ax += __uint_as_float(vv << 16);
            ay += __uint_as_float(vv & 0xffff0000u);
        }
        while (cur < nodeEnd) {                   // flush trailing (incl. empty) nodes
            int node = b * 64 + cur;
            int d = coff[cur + 1] - coff[cur];
            float inv = 1.0f / (float)(d > 1 ? d : 1);
            unsigned int o = (unsigned int)f32_to_bf16_rne(ax * inv)
                           | ((unsigned int)f32_to_bf16_rne(ay * inv) << 16);
            if (node < n)
                *(unsigned int*)(aggb + (size_t)node * 128 + lane * 2) = o;
            ax = 0.f; ay = 0.f; cur++;
        }
        return;
    }

    // ---- fallback: multi-chunk bucket (R9 path) ----
    float accx[16], accy[16];
    int dcnt[16];
#pragma unroll
    for (int nl = 0; nl < 16; nl++) { accx[nl] = 0.f; accy[nl] = 0.f; dcnt[nl] = 0; }
    for (int base = p0; base < p1; base += CHUNK) {
        int m = p1 - base; if (m > CHUNK) m = CHUNK;
        for (int i = tid; i < m; i += 256) stage[i] = esrt[base + i];
        if (tid < 64) cnt[tid] = 0;
        __syncthreads();
        for (int i = tid; i < m; i += 256) atomicAdd(&cnt[(stage[i] >> 17) & 63], 1);
        __syncthreads();
        if (tid < 64) {
            int v = cnt[tid];
            int x = v;
#pragma unroll
            for (int s = 1; s < 64; s <<= 1) {
                int y = __shfl_up(x, s);
                if (lane >= s) x += y;
            }
            coff[tid + 1] = x;
            if (tid == 0) coff[0] = 0;
            cnt[tid] = x - v;
        }
        __syncthreads();
        for (int i = tid; i < m; i += 256) {
            int pk = stage[i];
            int p = atomicAdd(&cnt[(pk >> 17) & 63], 1);
            sorted[p] = pk;
        }
        __syncthreads();
#pragma unroll
        for (int nl = 0; nl < 16; nl++) {
            int node_l = w * 16 + nl;
            int s = coff[node_l], e2 = coff[node_l + 1];
            dcnt[nl] += e2 - s;
            float ax = accx[nl], ay = accy[nl];
            int i = s;
            for (; i + 8 <= e2; i += 8) {
                unsigned int v[8];
#pragma unroll
                for (int j = 0; j < 8; j++) {
                    int sj = sorted[i + j] & 0x1FFFF;
                    v[j] = *(const unsigned int*)(hb + (size_t)sj * 128 + lane * 2);
                }
#pragma unroll
                for (int j = 0; j < 8; j++) {
                    ax += __uint_as_float(v[j] << 16);
                    ay += __uint_as_float(v[j] & 0xffff0000u);
                }
            }
            for (; i < e2; i++) {
                int sj = sorted[i] & 0x1FFFF;
                unsigned int vv = *(const unsigned int*)(hb + (size_t)sj * 128 + lane * 2);
                ax += __uint_as_float(vv << 16);
                ay += __uint_as_float(vv & 0xffff0000u);
            }
            accx[nl] = ax; accy[nl] = ay;
        }
        __syncthreads();
    }
#pragma unroll
    for (int nl = 0; nl < 16; nl++) {
        int node = b * 64 + w * 16 + nl;
        if (node < n) {
            int d = dcnt[nl];
            float inv = 1.0f / (float)(d > 1 ? d : 1);
            unsigned int o = (unsigned int)f32_to_bf16_rne(accx[nl] * inv)
                           | ((unsigned int)f32_to_bf16_rne(accy[nl] * inv) << 16);
            *(unsigned int*)(aggb + (size_t)node * 128 + lane * 2) = o;
        }
    }
}

// ---------------- fused SAGE update via split-bf16 MFMA ----------------
template <int LAYER, bool FINAL>
__global__ __launch_bounds__(256, 2) void update_mfma(
    const unsigned short* __restrict__ aggb, const void* __restrict__ hsrc,
    const uint4* __restrict__ Wsw, const float* __restrict__ bias,
    unsigned short* __restrict__ hout,
    const float* __restrict__ Wh, const float* __restrict__ bh,
    float* __restrict__ logits, int n) {
    __shared__ uint4 Alds[2048];
    __shared__ uint4 Wlds[2048];
    const int tid = threadIdx.x;
    const int lane = tid & 63;
    const int w = tid >> 6;
    const int i0 = blockIdx.x * 128;

    f32x4 acc[2][8];
#pragma unroll
    for (int mt = 0; mt < 2; mt++)
#pragma unroll
        for (int nt = 0; nt < 8; nt++) acc[mt][nt] = (f32x4)0.f;

    const int r = tid >> 1;
    const int half = tid & 1;
    const int rg = i0 + r;
    const bool inb = rg < n;
    const int mt_s = r >> 4;
    const int lidx = r & 15;

    for (int c = 0; c < 4; c++) {
        const bool haslo = (LAYER == 0 && c >= 2);
        {
            const uint4* srcW = Wsw + (size_t)c * 2048;
#pragma unroll
            for (int g = 0; g < 8; g++) Wlds[g * 256 + tid] = srcW[g * 256 + tid];
        }
        {
            unsigned short hiA[32], loA[32];
            if (LAYER == 0 && c >= 2) {
                const float4* s4 = (const float4*)((const float*)hsrc + (size_t)rg * 128 +
                                                   (c - 2) * 64 + half * 32);
#pragma unroll
                for (int q = 0; q < 8; q++) {
                    float4 f = inb ? s4[q] : make_float4(0.f, 0.f, 0.f, 0.f);
                    float vv[4] = {f.x, f.y, f.z, f.w};
#pragma unroll
                    for (int e = 0; e < 4; e++) {
                        unsigned short h = f32_to_bf16_rne(vv[e]);
                        hiA[q * 4 + e] = h;
                        loA[q * 4 + e] = f32_to_bf16_rne(vv[e] - bf16_bits_to_f32(h));
                    }
                }
            } else {
                const unsigned short* bsrc = (c < 2) ? aggb : (const unsigned short*)hsrc;
                int cc = (c < 2) ? c : c - 2;
                const uint4* s4 = (const uint4*)(bsrc + (size_t)rg * 128 + cc * 64 + half * 32);
#pragma unroll
                for (int q = 0; q < 4; q++) {
                    uint4 u = inb ? s4[q] : make_uint4(0, 0, 0, 0);
                    unsigned int uu[4] = {u.x, u.y, u.z, u.w};
#pragma unroll
                    for (int e = 0; e < 4; e++) {
                        hiA[q * 8 + e * 2 + 0] = (unsigned short)(uu[e] & 0xffffu);
                        hiA[q * 8 + e * 2 + 1] = (unsigned short)(uu[e] >> 16);
                    }
                }
            }
            unsigned int baseHi = ((mt_s * 2 + half) * 2 + 0) * 64;
#pragma unroll
            for (int g2 = 0; g2 < 4; g2++)
                Alds[baseHi + lidx + 16 * g2] = pack8(&hiA[g2 * 8]);
            if (haslo) {
#pragma unroll
                for (int g2 = 0; g2 < 4; g2++)
                    Alds[baseHi + 64 + lidx + 16 * g2] = pack8(&loA[g2 * 8]);
            }
        }
        __syncthreads();
#pragma unroll
        for (int kt = 0; kt < 2; kt++) {
            bf16x8 a0h = *(const bf16x8*)&Alds[(((w * 2 + 0) * 2 + kt) * 2 + 0) * 64 + lane];
            bf16x8 a1h = *(const bf16x8*)&Alds[(((w * 2 + 1) * 2 + kt) * 2 + 0) * 64 + lane];
            bf16x8 a0l, a1l;
            if (haslo) {
                a0l = *(const bf16x8*)&Alds[(((w * 2 + 0) * 2 + kt) * 2 + 1) * 64 + lane];
                a1l = *(const bf16x8*)&Alds[(((w * 2 + 1) * 2 + kt) * 2 + 1) * 64 + lane];
            }
#pragma unroll
            for (int nt = 0; nt < 8; nt++) {
                bf16x8 bhv = *(const bf16x8*)&Wlds[((kt * 8 + nt) * 2 + 0) * 64 + lane];
                bf16x8 blv = *(const bf16x8*)&Wlds[((kt * 8 + nt) * 2 + 1) * 64 + lane];
                acc[0][nt] = __builtin_amdgcn_mfma_f32_16x16x32_bf16(a0h, bhv, acc[0][nt], 0, 0, 0);
                acc[0][nt] = __builtin_amdgcn_mfma_f32_16x16x32_bf16(a0h, blv, acc[0][nt], 0, 0, 0);
                acc[1][nt] = __builtin_amdgcn_mfma_f32_16x16x32_bf16(a1h, bhv, acc[1][nt], 0, 0, 0);
                acc[1][nt] = __builtin_amdgcn_mfma_f32_16x16x32_bf16(a1h, blv, acc[1][nt], 0, 0, 0);
                if (haslo) {
                    acc[0][nt] = __builtin_amdgcn_mfma_f32_16x16x32_bf16(a0l, bhv, acc[0][nt], 0, 0, 0);
                    acc[1][nt] = __builtin_amdgcn_mfma_f32_16x16x32_bf16(a1l, bhv, acc[1][nt], 0, 0, 0);
                }
            }
        }
        __syncthreads();
    }

    const int col = lane & 15;
    const int g4 = lane >> 4;
    float bcol[8];
#pragma unroll
    for (int nt = 0; nt < 8; nt++) bcol[nt] = bias[nt * 16 + col];
    if (!FINAL) {
#pragma unroll
        for (int mt = 0; mt < 2; mt++) {
            int nodeBase = i0 + (w * 2 + mt) * 16 + g4 * 4;
#pragma unroll
            for (int reg = 0; reg < 4; reg++) {
                int node = nodeBase + reg;
                if (node < n) {
#pragma unroll
                    for (int nt = 0; nt < 8; nt++) {
                        float v = acc[mt][nt][reg] + bcol[nt];
                        v = v > 0.f ? v : 0.f;
                        hout[(size_t)node * 128 + nt * 16 + col] = f32_to_bf16_rne(v);
                    }
                }
            }
        }
    } else {
        float whc[8];
#pragma unroll
        for (int nt = 0; nt < 8; nt++) whc[nt] = Wh[nt * 16 + col];
        float bhv = bh[0];
#pragma unroll
        for (int mt = 0; mt < 2; mt++) {
            int nodeBase = i0 + (w * 2 + mt) * 16 + g4 * 4;
#pragma unroll
            for (int reg = 0; reg < 4; reg++) {
                float s = 0.f;
#pragma unroll
                for (int nt = 0; nt < 8; nt++) {
                    float v = acc[mt][nt][reg] + bcol[nt];
                    v = v > 0.f ? v : 0.f;
                    s += v * whc[nt];
                }
                s += __shfl_xor(s, 1);
                s += __shfl_xor(s, 2);
                s += __shfl_xor(s, 4);
                s += __shfl_xor(s, 8);
                int node = nodeBase + reg;
                if (col == 0 && node < n) logits[node] = s + bhv;
            }
        }
    }
}

extern "C" void kernel_launch(void* const* d_in, const int* in_sizes, int n_in,
                              void* d_out, int out_size, void* d_ws, size_t ws_size,
                              hipStream_t stream) {
    const float* x   = (const float*)d_in[0];
    const int*   ei  = (const int*)d_in[1];
    const float* Wn0 = (const float*)d_in[2];
    const float* Wr0 = (const float*)d_in[3];
    const float* b0  = (const float*)d_in[4];
    const float* Wn1 = (const float*)d_in[5];
    const float* Wr1 = (const float*)d_in[6];
    const float* b1  = (const float*)d_in[7];
    const float* Wh  = (const float*)d_in[8];
    const float* bh  = (const float*)d_in[9];
    float* logits = (float*)d_out;

    int N = in_sizes[0] / 128;
    int E = in_sizes[1] / 2;
    const int* src = ei;
    const int* dst = ei + E;

    int nbkt = (N + 63) >> 6;                       // 64-node coarse buckets
    int HS = nbkt * NSB;                            // histogram entries
    int NB = (HS + 2047) / 2048;                    // scan1 blocks
    int chunk = (((E + NSB - 1) / NSB) + 3) & ~3;   // multiple of 4 for int4 path

    char* ws = (char*)d_ws;
    size_t cur = 0;
    auto alloc = [&](size_t bytes) -> void* {
        void* p = ws + cur;
        cur += (bytes + 255) & ~(size_t)255;
        return p;
    };
    int* hist  = (int*)alloc((size_t)HS * 4);
    int* bsums = (int*)alloc((size_t)NB * 4);
    int* bbase = (int*)alloc((size_t)NB * 4);
    int* scrat = (int*)alloc(256);
    int* esrt  = (int*)alloc((size_t)E * 4);
    unsigned short* xb  = (unsigned short*)alloc((size_t)N * 128 * 2);
    unsigned short* h0b = (unsigned short*)alloc((size_t)N * 128 * 2);
    unsigned short* agb = (unsigned short*)alloc((size_t)N * 128 * 2);
    uint4* Wsw0 = (uint4*)alloc(131072);
    uint4* Wsw1 = (uint4*)alloc(131072);
    (void)ws_size; (void)n_in; (void)out_size;

    // precision prep
    int n4 = N * 32;
    hipLaunchKernelGGL(cvt_bf16_kernel, dim3((n4 + 255) / 256), dim3(256), 0, stream,
                       (const float4*)x, (ushort4*)xb, n4);
    hipLaunchKernelGGL(swizzle_w_kernel, dim3(16), dim3(256), 0, stream, Wn0, Wr0, Wsw0);
    hipLaunchKernelGGL(swizzle_w_kernel, dim3(16), dim3(256), 0, stream, Wn1, Wr1, Wsw1);

    // coarse counting sort (NSB=128, int4 edge reads)
    hipLaunchKernelGGL(hist64,        dim3(NSB), dim3(256), 0, stream, dst, hist, E, nbkt, chunk);
    hipLaunchKernelGGL(scan1_kernel,  dim3(NB),  dim3(256), 0, stream, hist, hist, bsums, HS);
    hipLaunchKernelGGL(scan2_kernel,  dim3(1),   dim3(64),  0, stream, bsums, bbase, NB, scrat);
    hipLaunchKernelGGL(scan3b_kernel, dim3((HS + 255) / 256), dim3(256), 0, stream, hist, bbase, HS);
    hipLaunchKernelGGL(scatter64,     dim3(NSB), dim3(256), 0, stream, src, dst, hist, esrt, E, nbkt, chunk);

    int gUpd = (N + 127) / 128;

    // Layer 0
    hipLaunchKernelGGL(agg_bucket, dim3(nbkt), dim3(256), 0, stream, xb, hist, esrt, agb, E, nbkt, N);
    hipLaunchKernelGGL((update_mfma<0, false>), dim3(gUpd), dim3(256), 0, stream,
                       agb, (const void*)x, Wsw0, b0, h0b, nullptr, nullptr, nullptr, N);
    // Layer 1 + fused head
    hipLaunchKernelGGL(agg_bucket, dim3(nbkt), dim3(256), 0, stream, h0b, hist, esrt, agb, E, nbkt, N);
    hipLaunchKernelGGL((update_mfma<1, true>), dim3(gUpd), dim3(256), 0, stream,
                       agb, (const void*)h0b, Wsw1, b1, nullptr, Wh, bh, logits, N);
}